// Round 5
// baseline (10009.858 us; speedup 1.0000x reference)
//
#include <hip/hip_runtime.h>

// HMM forward: alpha_t = (alpha_{t-1} @ A) * B[:, obs_t], out = sum(alpha_{T-1})
// S=2048, V=32768, T=4096. Persistent cooperative kernel.
//
// R8 = R7 + two deterministic-failure fixes after R7 killed the container
// twice (R4-R6 ran fine on the same harness => kernel-side cause likely):
//   1. __launch_bounds__(BT, 2): R7 used (BT,1), authorizing a 512-VGPR
//      budget. A-in-regs pins 64 VGPRs + ~100 temporaries; if the allocator
//      exceeded 256 VGPRs, an 8-wave block can NEVER be scheduled on a CU
//      (>256 VGPR => 4 waves/CU max) and the cooperative launch fails every
//      attempt = "container failed twice". (BT,2) pins the 256 cap.
//   2. Budgeted polls: per-thread spin budget (1<<23 iters ~ 2s worst case,
//      ~200x legit margin). Exhaustion => break with garbage => kernel
//      terminates => absmax!=0 verdict instead of a dead container.
//
// R7 core (unchanged): A held PERMANENTLY IN REGISTERS.
//   - thread (rg=tid>>2, cq=tid&3) owns rows rg*16..+15 x cols 4cq..+3 of the
//     block's A slice = 64 floats = 64 VGPRs, loaded once from global, pinned.
//   - NO per-step A LDS reads (R5/R6's 128 ds_read_b128/step carried ~3e8
//     conflict cycles two swizzles failed to kill -> access class removed).
//   - LDS ~10KB static: quad-share + b-ring + partials. One barrier per step.
//   - b prefetch issued BEFORE the poll so HBM latency hides under the wait.
//
// Evidence trail:
//  - R1/R3: scattered multi-writer publish => partial-line write-throughs
//    serializing the critical path. Publish stays ONE coalesced 128B line.
//  - R4: 2.37us/step, VALUBusy 10%, HBM 1%: latency-bound relay.
//  - R5: C=4 cols/thread dot: -115ns/step real. Best measured: 9022us rocprof.
//  - R6: quad-share + 1 barrier: neutral; af swizzle fix #2 failed.

#define S 2048
#define V 32768
#define T 4096
#define G 128          // blocks, cooperative, 1 per CU
#define BT 512         // 8 waves
#define COLS 16        // columns of A per block
#define RING 16        // b-value ring slots
#define DIST 8         // b prefetch distance (steps)
#define POLL_BUDGET (1 << 23)   // ~200x any legitimate whole-kernel spin

__global__ __launch_bounds__(BT, 2) void hmm_fwd(
    const int* __restrict__ obs,
    const float* __restrict__ A,
    const float* __restrict__ B,
    const float* __restrict__ pi,
    float* __restrict__ out,
    unsigned long long* __restrict__ buf)   // 2 * S pairs of {tag32, f32}
{
    __shared__ float4 sh4[BT];          // quad-share: slot = tid
    __shared__ float  bring[RING * COLS];
    __shared__ float  wpart[2][128];    // parity double-buffer
    __shared__ float  fpart[8];

    const int g    = blockIdx.x;
    const int tid  = threadIdx.x;
    const int lane = tid & 63;
    const int wave = tid >> 6;
    const int cq   = tid & 3;             // column quad: cols 4cq..4cq+3
    const int rg   = tid >> 2;            // row group 0..127 (rows rg*16..+15)

    int budget = POLL_BUDGET;             // shared across all polls, per thread

    // ---- one-time: load this thread's A fragment into pinned registers.
    // rows rg*16..+15, cols g*16+4cq..+3. Quad lanes read 64B contiguous.
    float4 af[16];
    {
        const float* ap = A + (size_t)(rg * 16) * S + g * COLS + cq * 4;
#pragma unroll
        for (int r = 0; r < 16; ++r)
            af[r] = *(const float4*)(ap + (size_t)r * S);
#pragma unroll
        for (int r = 0; r < 16; ++r)
            asm volatile("" : "+v"(af[r].x), "+v"(af[r].y),
                              "+v"(af[r].z), "+v"(af[r].w));
    }

    // ---- wave 1: init b-ring (t=1..DIST). wave 0: publish alpha_0 (tag 1).
    if (wave == 1 && lane < COLS) {
        int jj = g * COLS + lane;
        for (int u = 1; u <= DIST; ++u) {
            int o = obs[u];
            bring[(u & (RING - 1)) * COLS + lane] = B[(size_t)jj * V + o];
        }
    }
    if (wave == 0 && lane < COLS) {
        int jl = g * COLS + lane;
        int o0 = obs[0];
        float v = pi[jl] * B[(size_t)jl * V + o0];
        unsigned long long p = (1ull << 32) | (unsigned long long)__float_as_uint(v);
        __hip_atomic_store(&buf[jl], p, __ATOMIC_RELAXED, __HIP_MEMORY_SCOPE_AGENT);
    }

    __syncthreads();   // ring init + alpha_0 ordered before first use

    for (int t = 1; t < T; ++t) {
        // ---- b prefetch for t+DIST, issued BEFORE the poll so the HBM
        // latency is absorbed by the wait (wave 1, off critical path).
        if (wave == 1 && lane < COLS) {
            int tp = t + DIST;
            if (tp < T) {
                int o = obs[tp];
                bring[(tp & (RING - 1)) * COLS + lane] =
                    B[(size_t)(g * COLS + lane) * V + o];
            }
        }

        // ---- poll ONLY this thread's 4 alpha entries (tag == t): 32B at
        // entries 4*tid..+3 (= one quarter of publisher block rg's line).
        unsigned long long want = (unsigned long long)t;
        unsigned long long* src = buf + (((t - 1) & 1) * S) + 4 * tid;
        unsigned long long v0, v1, v2, v3;
        for (;;) {
            v0 = __hip_atomic_load(&src[0], __ATOMIC_RELAXED, __HIP_MEMORY_SCOPE_AGENT);
            v1 = __hip_atomic_load(&src[1], __ATOMIC_RELAXED, __HIP_MEMORY_SCOPE_AGENT);
            v2 = __hip_atomic_load(&src[2], __ATOMIC_RELAXED, __HIP_MEMORY_SCOPE_AGENT);
            v3 = __hip_atomic_load(&src[3], __ATOMIC_RELAXED, __HIP_MEMORY_SCOPE_AGENT);
            if ((v0 >> 32) == want && (v1 >> 32) == want &&
                (v2 >> 32) == want && (v3 >> 32) == want) break;
            if (--budget < 0) break;      // terminate-with-garbage, not hang
            __builtin_amdgcn_s_sleep(1);
        }
        float4 f;
        f.x = __uint_as_float((unsigned)v0);
        f.y = __uint_as_float((unsigned)v1);
        f.z = __uint_as_float((unsigned)v2);
        f.w = __uint_as_float((unsigned)v3);

        // ---- intra-wave quad share (lockstep, NO barrier): quad of lanes
        // 4m..4m+3 pools its 4x float4 = the 16 alpha rows rg*16..+15.
        sh4[tid] = f;
        int qb = tid & ~3;
        float4 al0 = sh4[qb + 0];
        float4 al1 = sh4[qb + 1];
        float4 al2 = sh4[qb + 2];
        float4 al3 = sh4[qb + 3];

        // ---- dot: 16 rows x 4 cols; A and alpha both in registers
        float4 acc = {0.f, 0.f, 0.f, 0.f};
#define DOT4(AL, B0)                                         \
        {                                                    \
            float4 a0 = af[(B0) + 0];                        \
            float4 a1 = af[(B0) + 1];                        \
            float4 a2 = af[(B0) + 2];                        \
            float4 a3 = af[(B0) + 3];                        \
            acc.x = fmaf(AL.x, a0.x, acc.x);                 \
            acc.x = fmaf(AL.y, a1.x, acc.x);                 \
            acc.x = fmaf(AL.z, a2.x, acc.x);                 \
            acc.x = fmaf(AL.w, a3.x, acc.x);                 \
            acc.y = fmaf(AL.x, a0.y, acc.y);                 \
            acc.y = fmaf(AL.y, a1.y, acc.y);                 \
            acc.y = fmaf(AL.z, a2.y, acc.y);                 \
            acc.y = fmaf(AL.w, a3.y, acc.y);                 \
            acc.z = fmaf(AL.x, a0.z, acc.z);                 \
            acc.z = fmaf(AL.y, a1.z, acc.z);                 \
            acc.z = fmaf(AL.z, a2.z, acc.z);                 \
            acc.z = fmaf(AL.w, a3.z, acc.z);                 \
            acc.w = fmaf(AL.x, a0.w, acc.w);                 \
            acc.w = fmaf(AL.y, a1.w, acc.w);                 \
            acc.w = fmaf(AL.z, a2.w, acc.w);                 \
            acc.w = fmaf(AL.w, a3.w, acc.w);                 \
        }
        DOT4(al0, 0)
        DOT4(al1, 4)
        DOT4(al2, 8)
        DOT4(al3, 12)
#undef DOT4

        // lane = m*4 + cq; reduce across the 16 m's within the wave
#pragma unroll
        for (int off = 32; off >= 4; off >>= 1) {
            acc.x += __shfl_down(acc.x, off, 64);
            acc.y += __shfl_down(acc.y, off, 64);
            acc.z += __shfl_down(acc.z, off, 64);
            acc.w += __shfl_down(acc.w, off, 64);
        }
        float* wp = wpart[t & 1];
        if (lane < 4)   // m==0: lane holds cols lane*4..lane*4+3
            *(float4*)(wp + wave * 16 + lane * 4) = acc;
        __syncthreads();   // B2: partials ready (ONLY barrier per step)

        // ---- epilogue: wave 0 sums, applies b_t, ONE coalesced 128B publish
        if (wave == 0 && lane < 16) {
            float s = 0.f;
#pragma unroll
            for (int w = 0; w < 8; ++w) s += wp[w * 16 + lane];
            float val = s * bring[(t & (RING - 1)) * COLS + lane];
            unsigned long long p = (((unsigned long long)(t + 1)) << 32) |
                                   (unsigned long long)__float_as_uint(val);
            __hip_atomic_store(&buf[(t & 1) * S + g * COLS + lane], p,
                               __ATOMIC_RELAXED, __HIP_MEMORY_SCOPE_AGENT);
        }
    }

    // ---- final: block 0 sums alpha_{T-1} (tag == T) into out[0]
    if (g == 0) {
        unsigned long long want = (unsigned long long)T;
        unsigned long long* src = buf + (((T - 1) & 1) * S) + 4 * tid;
        unsigned long long v0, v1, v2, v3;
        for (;;) {
            v0 = __hip_atomic_load(&src[0], __ATOMIC_RELAXED, __HIP_MEMORY_SCOPE_AGENT);
            v1 = __hip_atomic_load(&src[1], __ATOMIC_RELAXED, __HIP_MEMORY_SCOPE_AGENT);
            v2 = __hip_atomic_load(&src[2], __ATOMIC_RELAXED, __HIP_MEMORY_SCOPE_AGENT);
            v3 = __hip_atomic_load(&src[3], __ATOMIC_RELAXED, __HIP_MEMORY_SCOPE_AGENT);
            if ((v0 >> 32) == want && (v1 >> 32) == want &&
                (v2 >> 32) == want && (v3 >> 32) == want) break;
            if (--budget < 0) break;      // terminate-with-garbage, not hang
            __builtin_amdgcn_s_sleep(1);
        }
        float sm = __uint_as_float((unsigned)v0) + __uint_as_float((unsigned)v1) +
                   __uint_as_float((unsigned)v2) + __uint_as_float((unsigned)v3);
        sm += __shfl_down(sm, 32, 64);
        sm += __shfl_down(sm, 16, 64);
        sm += __shfl_down(sm, 8, 64);
        sm += __shfl_down(sm, 4, 64);
        sm += __shfl_down(sm, 2, 64);
        sm += __shfl_down(sm, 1, 64);
        if (lane == 0) fpart[wave] = sm;
        __syncthreads();
        if (tid == 0) {
            float tot = 0.f;
            for (int w = 0; w < 8; ++w) tot += fpart[w];
            out[0] = tot;
        }
    }
}

extern "C" void kernel_launch(void* const* d_in, const int* in_sizes, int n_in,
                              void* d_out, int out_size, void* d_ws, size_t ws_size,
                              hipStream_t stream) {
    const int*   obs = (const int*)d_in[0];
    const float* A   = (const float*)d_in[1];
    const float* B   = (const float*)d_in[2];
    const float* pi  = (const float*)d_in[3];
    float* out = (float*)d_out;
    unsigned long long* buf = (unsigned long long*)d_ws;  // 2*S*8 = 32 KB

    // No memset needed: 0xAA poison tag 0xAAAAAAAA never matches tags [1,4096].

    void* args[] = { (void*)&obs, (void*)&A, (void*)&B, (void*)&pi,
                     (void*)&out, (void*)&buf };
    hipLaunchCooperativeKernel((void*)hmm_fwd, dim3(G), dim3(BT), args,
                               0, stream);
}